// Round 9
// baseline (70.718 us; speedup 1.0000x reference)
//
#include <hip/hip_runtime.h>

// YOLO layer: x (32, 255, 76, 76) fp32 -> out (32, 76*76*3, 85) fp32
// out flat = b*(76*76*255) + h*(76*255) + w*255 + (a*85 + attr)
//          = f(x[b][a*85+attr][h][w])
//   attr 0: (sigmoid(v) + w) * 8     attr 2: exp(v) * {10,16,33}[a]
//   attr 1: (sigmoid(v) + h) * 8     attr 3: exp(v) * {13,30,23}[a]
//   else  : sigmoid(v)
//
// ROUND-9 = ROUND-5 BASE + PHASE-MIXED SCATTER/STORE (loads untouched).
// R8 falsified burst-collision (stagger = pure cost); R6/R7 falsified
// w-split LOADS (partial-line re-fetch, FETCH +87..115 MB). Remaining
// theory: R5's dedicated phases (pure-LDS scatter | barrier | pure-vmem
// store) idle the memory system half the time. Fix that WITHOUT touching
// the load pattern: scatter target 4*c*C+row partitions the buffer at
// c=10 -> A = f4 [0,2550), B = [2550,4845). Split only scatter+store:
//   region 1: scatter B(t) | issue FULL tile t+1 | store A(t)  -- barrier
//   region 2: scatter A(t+1) | store B(t)                      -- barrier
// Every region mixes LDS-transform + a ~40 KB contiguous store (disjoint
// LDS ranges, scheduler can interleave). Hazards: store-read vs next
// region-write separated by one barrier; stage WAR (scatterB before issue)
// by program order. Per-thread state = stage[5]+offk[5] (R5-proven, no
// spill under the 64-VGPR cap).

typedef float f4 __attribute__((ext_vector_type(4)));

constexpr int NBATCH = 32;
constexpr int NH = 76;
constexpr int NW = 76;
constexpr int C = 255;                 // 3 anchors * 85
constexpr int ROW_F4 = NW / 4;         // 19 f4 per input row
constexpr int BLK_F4 = C * ROW_F4;     // 4845 f4 per tile
constexpr int TILES = NBATCH * NH;     // 2432
constexpr int NTH = 1024;
constexpr int KMAX = 5;                // ceil(4845/1024)
constexpr int TAIL = BLK_F4 - 4 * NTH; // 749 (k==4 active threads)
constexpr int GRID = 512;              // 2 blocks per CU
constexpr int NXCD = 8;
constexpr int PER_XCD = TILES / NXCD;        // 304
constexpr int BPX = GRID / NXCD;             // 64 blocks per XCD
constexpr int AF4 = 2550;              // c in [0,10): w 0..39
constexpr int BF4 = BLK_F4 - AF4;      // 2295: c in [10,19): w 40..75
constexpr int TAILA = AF4 - 2 * NTH;   // 502
constexpr int TAILB = BF4 - 2 * NTH;   // 247
constexpr float STRIDE = 8.0f;

__global__ __launch_bounds__(NTH, 8) void yolo_kernel(const f4* __restrict__ x4,
                                                      f4* __restrict__ out4) {
    __shared__ f4 buf[BLK_F4];         // 77520 B -> 2 blocks/CU
    float* __restrict__ tb = (float*)buf;

    const int tid = threadIdx.x;

    // ---- only persistent per-thread array: tile-invariant input offsets ----
    int offk[KMAX];
#pragma unroll
    for (int k = 0; k < KMAX; ++k) {
        const int i = tid + k * NTH;
        const int ii = (k < 4 || tid < TAIL) ? i : 0;
        const int row = ii / ROW_F4;           // channel 0..254
        const int c = ii - row * ROW_F4;       // f4 index along w
        offk[k] = row * (NH * ROW_F4) + c;
    }

    // ---- XCD-contiguous tile assignment ----
    const int x = blockIdx.x & (NXCD - 1);     // XCD (dispatch round-robin)
    const int j = blockIdx.x >> 3;             // block index within XCD, 0..63
    const int base_t = x * PER_XCD;
    const int ntile = 4 + (j < (PER_XCD - 4 * BPX) ? 1 : 0);  // 4 or 5

    f4 stage[KMAX];

    auto issue = [&](int t) {                  // FULL tile: 19-f4 runs (R5)
        const int b = t / NH;
        const int h = t - b * NH;
        const size_t inb = (size_t)b * (C * NH * ROW_F4) + (size_t)h * ROW_F4;
#pragma unroll
        for (int k = 0; k < KMAX; ++k)
            if (k < 4 || tid < TAIL) stage[k] = x4[inb + offk[k]];
    };

    // fused transform + scatter for one half: selB=false -> c<10 (A region),
    // selB=true -> c>=10 (B region). Transform math identical to R5.
    auto scatter = [&](int t, bool selB) {
        const float hf = (float)(t % NH);
#pragma unroll
        for (int k = 0; k < KMAX; ++k) {
            if (!(k < 4 || tid < TAIL)) continue;
            const int i = tid + k * NTH;
            const int row = i / ROW_F4;        // channel 0..254
            const int c = i - row * ROW_F4;
            if (selB ? (c < 10) : (c >= 10)) continue;
            const int a = (row >= 85 ? 1 : 0) + (row >= 170 ? 1 : 0);
            const int attr = row - 85 * a;
            const bool m3 = (attr == 2) || (attr == 3);
            const bool m12 = attr < 2;
            const float aw = (a == 0) ? 10.f : ((a == 1) ? 16.f : 33.f);
            const float ah = (a == 0) ? 13.f : ((a == 1) ? 30.f : 23.f);
            const float aux3 = (attr == 2) ? aw : ah;
            const float w0 = (float)(4 * c);
            const int base = 4 * c * C + row;  // A: <10200 floats; B: >=10200

            const f4 v = stage[k];
            f4 r;
#pragma unroll
            for (int e = 0; e < 4; ++e) {
                const float ve = v[e];
                const float E = __expf(m3 ? ve : -ve);  // one exp per element
                const float sg = 1.0f / (1.0f + E);
                const float add = (attr == 0) ? (w0 + (float)e) : hf;
                float o = m3 ? (E * aux3) : sg;
                if (m12) o = (sg + add) * STRIDE;
                r[e] = o;
            }
            tb[base]         = r.x;
            tb[base + C]     = r.y;
            tb[base + 2 * C] = r.z;
            tb[base + 3 * C] = r.w;
        }
    };

    auto storeA = [&](int t) {                 // f4 [0, 2550) contiguous
        const size_t ob = (size_t)t * BLK_F4;
#pragma unroll
        for (int k = 0; k < 3; ++k) {
            const int i = tid + k * NTH;
            if (k < 2 || tid < TAILA)
                __builtin_nontemporal_store(buf[i], &out4[ob + i]);
        }
    };
    auto storeB = [&](int t) {                 // f4 [2550, 4845) contiguous
        const size_t ob = (size_t)t * BLK_F4 + AF4;
#pragma unroll
        for (int k = 0; k < 3; ++k) {
            const int i = tid + k * NTH;
            if (k < 2 || tid < TAILB)
                __builtin_nontemporal_store(buf[AF4 + i], &out4[ob + i]);
        }
    };

    // ---- prologue: fill A(t0) ----
    int t = base_t + j;
    issue(t);
    scatter(t, false);                         // A(t0) -> buf[0,2550)
    __syncthreads();

    int idx = 0;
    while (true) {
        const bool more = (idx + 1 < ntile);
        const int tn = more ? (base_t + (idx + 1) * BPX + j) : 0;

        // region 1: scatter B(t) | issue(t+1) | store A(t)
        scatter(t, true);                      // reads stage(t), writes B-region
        if (more) issue(tn);                   // stage <- t+1 (WAR, prog order)
        storeA(t);                             // reads A-region (disjoint)
        __syncthreads();

        if (!more) {                           // epilogue: B(t) already in LDS
            storeB(t);
            break;
        }

        // region 2: scatter A(t+1) | store B(t)
        scatter(tn, false);                    // writes A-region
        storeB(t);                             // reads B-region (disjoint)
        __syncthreads();

        t = tn;
        ++idx;
    }
}

extern "C" void kernel_launch(void* const* d_in, const int* in_sizes, int n_in,
                              void* d_out, int out_size, void* d_ws, size_t ws_size,
                              hipStream_t stream) {
    const f4* x4 = (const f4*)d_in[0];
    f4* out4 = (f4*)d_out;
    yolo_kernel<<<GRID, NTH, 0, stream>>>(x4, out4);
}

// Round 10
// 64.085 us; speedup vs baseline: 1.1035x; 1.1035x over previous
//
#include <hip/hip_runtime.h>

// YOLO layer: x (32, 255, 76, 76) fp32 -> out (32, 76*76*3, 85) fp32
// out flat = b*(76*76*255) + h*(76*255) + w*255 + (a*85 + attr)
//          = f(x[b][a*85+attr][h][w])
//   attr 0: (sigmoid(v) + w) * 8     attr 2: exp(v) * {10,16,33}[a]
//   attr 1: (sigmoid(v) + h) * 8     attr 3: exp(v) * {13,30,23}[a]
//   else  : sigmoid(v)
//
// FINAL = ROUND-5 KERNEL (best measured: 63.8 us, HBM traffic at ideal).
// Structure: persistent single-buffer pipeline, 2 blocks/CU (512 blocks,
// 4-5 tiles each), XCD-contiguous tile map, fused in-register transform
// (one transcendental per element) + LDS scatter-transpose, contiguous
// ds_read_b128 + nontemporal f4 stores. Per-thread state = stage[5]+offk[5]
// only (anything more spills under the 64-VGPR/2-blocks-per-CU cap and
// shows up as scratch traffic in FETCH/WRITE_SIZE).
//
// Session ledger (why this shape is final):
//   R6 ping-pong half-tiles:     103.6 us  (two stage sets -> scratch spill)
//   R7 single-stage ping-pong:    91.2 us  (w-split loads -> +87 MB fetch)
//   R8 CU-pair antiphase stagger: 69.7 us  (burst-collision theory false)
//   R9 region-split scatter/store:70.7 us  (doubled scatter VALU overhead)
// R5 = 377 MB CU-side / 63.8 us = 5.91 TB/s = 94% of the m13 copy ceiling
// (6.29 TB/s); remaining ~5% = 2432/512 = 4.75 -> 5-period quantization
// tail, not recoverable without tile splits that were measured to inflate
// HBM traffic. This is the roofline for this op.

typedef float f4 __attribute__((ext_vector_type(4)));

constexpr int NBATCH = 32;
constexpr int NH = 76;
constexpr int NW = 76;
constexpr int C = 255;                 // 3 anchors * 85
constexpr int ROW_F4 = NW / 4;         // 19 f4 per input row
constexpr int BLK_F4 = C * ROW_F4;     // 4845 f4 per tile
constexpr int TILES = NBATCH * NH;     // 2432
constexpr int NTH = 1024;
constexpr int KMAX = 5;                // ceil(4845/1024)
constexpr int TAIL = BLK_F4 - 4 * NTH; // 749 (k==4 active threads)
constexpr int GRID = 512;              // 2 blocks per CU
constexpr int NXCD = 8;
constexpr int PER_XCD = TILES / NXCD;        // 304
constexpr int BPX = GRID / NXCD;             // 64 blocks per XCD
constexpr float STRIDE = 8.0f;

__global__ __launch_bounds__(NTH, 8) void yolo_kernel(const f4* __restrict__ x4,
                                                      f4* __restrict__ out4) {
    __shared__ f4 buf[BLK_F4];         // 77520 B -> 2 blocks/CU
    float* __restrict__ tb = (float*)buf;

    const int tid = threadIdx.x;

    // ---- only persistent per-thread array: tile-invariant input offsets ----
    int offk[KMAX];
#pragma unroll
    for (int k = 0; k < KMAX; ++k) {
        const int i = tid + k * NTH;
        const int ii = (k < 4 || tid < TAIL) ? i : 0;
        const int row = ii / ROW_F4;           // channel 0..254
        const int c = ii - row * ROW_F4;       // f4 index along w
        offk[k] = row * (NH * ROW_F4) + c;
    }

    // ---- XCD-contiguous tile assignment ----
    const int x = blockIdx.x & (NXCD - 1);     // XCD (dispatch round-robin)
    const int j = blockIdx.x >> 3;             // block index within XCD, 0..63
    const int base_t = x * PER_XCD;
    const int ntile = 4 + (j < (PER_XCD - 4 * BPX) ? 1 : 0);  // 4 or 5

    f4 stage[KMAX];

    auto issue = [&](int t) {
        const int b = t / NH;
        const int h = t - b * NH;
        const size_t inb = (size_t)b * (C * NH * ROW_F4) + (size_t)h * ROW_F4;
#pragma unroll
        for (int k = 0; k < KMAX; ++k)
            if (k < 4 || tid < TAIL) stage[k] = x4[inb + offk[k]];
    };

    int t = base_t + j;                        // tile for idx 0
    issue(t);
    int idx = 0;

    while (true) {
        const float hf = (float)(t % NH);      // block-uniform

        if (idx > 0) __syncthreads();          // prev store-phase reads done

        // ---- fused transform + scatter (descriptors recomputed, no arrays) ----
#pragma unroll
        for (int k = 0; k < KMAX; ++k) {
            if (!(k < 4 || tid < TAIL)) continue;
            const int i = tid + k * NTH;
            const int row = i / ROW_F4;        // channel 0..254
            const int c = i - row * ROW_F4;
            const int a = (row >= 85 ? 1 : 0) + (row >= 170 ? 1 : 0);
            const int attr = row - 85 * a;
            const bool m3 = (attr == 2) || (attr == 3);
            const bool m12 = attr < 2;
            const float aw = (a == 0) ? 10.f : ((a == 1) ? 16.f : 33.f);
            const float ah = (a == 0) ? 13.f : ((a == 1) ? 30.f : 23.f);
            const float aux3 = (attr == 2) ? aw : ah;
            const float w0 = (float)(4 * c);
            const int base = 4 * c * C + row;  // tile[w=4c+e][ch=row]

            const f4 v = stage[k];
            f4 r;
#pragma unroll
            for (int e = 0; e < 4; ++e) {
                const float ve = v[e];
                const float E = __expf(m3 ? ve : -ve);  // one exp per element
                const float sg = 1.0f / (1.0f + E);
                const float add = (attr == 0) ? (w0 + (float)e) : hf;
                float o = m3 ? (E * aux3) : sg;
                if (m12) o = (sg + add) * STRIDE;
                r[e] = o;
            }
            tb[base]         = r.x;
            tb[base + C]     = r.y;
            tb[base + 2 * C] = r.z;
            tb[base + 3 * C] = r.w;
        }

        const size_t ob = (size_t)t * BLK_F4;
        ++idx;
        const bool more = (idx < ntile);
        if (more) {                            // issue next tile's loads now:
            t = base_t + idx * BPX + j;
            issue(t);                          // latency hides under store phase
        }

        __syncthreads();                       // LDS writes visible

        // ---- pure streaming store: contiguous b128 reads + nt stores ----
#pragma unroll
        for (int k = 0; k < KMAX; ++k) {
            const int i = tid + k * NTH;
            if (k < 4 || tid < TAIL)
                __builtin_nontemporal_store(buf[i], &out4[ob + i]);
        }

        if (!more) break;
    }
}

extern "C" void kernel_launch(void* const* d_in, const int* in_sizes, int n_in,
                              void* d_out, int out_size, void* d_ws, size_t ws_size,
                              hipStream_t stream) {
    const f4* x4 = (const f4*)d_in[0];
    f4* out4 = (f4*)d_out;
    yolo_kernel<<<GRID, NTH, 0, stream>>>(x4, out4);
}